// Round 1
// baseline (38618.613 us; speedup 1.0000x reference)
//
#include <hip/hip_runtime.h>
#include <hip/hip_cooperative_groups.h>
#include <cstddef>

namespace cg = cooperative_groups;

#define BB   16
#define TT   1024
#define HH   512
#define PADW 516   // padded LDS row stride in floats (516*4 B, 16B-aligned, breaks 32-bank stride)

// 256 WGs x 256 threads. WG wg: layer = wg>>7, lw = wg&127 owns h-indices lw*4..lw*4+3.
// Per WG LDS: 16 gate rows x {input-matrix, recurrent-matrix} weights + staged activations.
__global__ __launch_bounds__(256, 1)
void lstm2_coop(const float* __restrict__ x,
                const float* __restrict__ h0,
                const float* __restrict__ c0,
                const float* __restrict__ w_ih0,
                const float* __restrict__ w_hh0,
                const float* __restrict__ b_ih0,
                const float* __restrict__ b_hh0,
                const float* __restrict__ w_ih1,
                const float* __restrict__ w_hh1,
                const float* __restrict__ b_ih1,
                const float* __restrict__ b_hh1,
                float* __restrict__ out,
                float* __restrict__ h1buf,   // [2][B][H] double buffer in ws
                float* __restrict__ h2buf)   // [2][B][H]
{
    __shared__ float w_lds[2 * 16 * PADW];    // 66048 B
    __shared__ float act_lds[2 * 16 * PADW];  // 66048 B  [0]=layer input act, [1]=h_prev
    __shared__ float partial[16 * 16 * 17];   // 17408 B  [row][b][mat*8+kc], pad 17
    __shared__ float gval[16 * 16];           // gate pre-activations [row][b]
    __shared__ float hout[16 * 4];            // new h [b][jj]
    __shared__ float bias_lds[16];            // b_ih[row]+b_hh[row]

    const int tid   = threadIdx.x;
    const int wg    = blockIdx.x;
    const int layer = wg >> 7;     // 0 or 1
    const int lw    = wg & 127;    // 0..127 -> h indices lw*4..+3

    const float* w_in  = layer ? w_ih1 : w_ih0;
    const float* w_rec = layer ? w_hh1 : w_hh0;
    const float* b_in  = layer ? b_ih1 : b_ih0;
    const float* b_rec = layer ? b_hh1 : b_hh0;
    float* hbuf_own = layer ? h2buf : h1buf;

    // ---- one-time: stage 32 weight rows (16 rows x 2 matrices) into LDS ----
    {
        const int mr   = tid >> 3;          // 0..31
        const int mat  = mr >> 4;           // 0 = input matrix, 1 = recurrent
        const int r    = mr & 15;           // r = gate*4 + jj
        const int gate = r >> 2;
        const int jj   = r & 3;
        const int grow = gate * HH + lw * 4 + jj;   // global gate-row index
        const float* srcw = (mat ? w_rec : w_in) + (size_t)grow * HH;
        float* dstw = w_lds + (mat * 16 + r) * PADW;
        const int seg = tid & 7;            // 64-float segment
        #pragma unroll
        for (int q = 0; q < 16; ++q) {
            const int k = seg * 64 + q * 4;
            *(float4*)(dstw + k) = *(const float4*)(srcw + k);
        }
        if (tid < 16) {
            const int g2 = tid >> 2, j2 = tid & 3;
            const int gr = g2 * HH + lw * 4 + j2;
            bias_lds[tid] = b_in[gr] + b_rec[gr];
        }
    }

    // ---- persistent c state: threads 0..63 own (b = tid>>2, jj = tid&3) ----
    float c_reg = 0.0f;
    if (tid < 64) {
        const int jj = tid & 3, b = tid >> 2;
        c_reg = c0[(size_t)layer * BB * HH + (size_t)b * HH + lw * 4 + jj];
    }

    __syncthreads();

    // dot-product thread roles: 4x4 (row-group x batch-group) tile per thread,
    // split over 2 matrices and 8 k-chunks of 64
    const int kc  = tid & 7;
    const int mat = (tid >> 3) & 1;
    const int bg  = (tid >> 4) & 3;
    const int rg  = tid >> 6;

    cg::grid_group grid = cg::this_grid();

    for (int it = 0; it <= TT; ++it) {
        const int t = layer ? (it - 1) : it;   // layer 2 runs one step behind layer 1
        if (t >= 0 && t < TT) {
            // ---- stage activations: act0 = layer input at t, act1 = own h(t-1) ----
            {
                const int arr = tid >> 7;      // 128 threads per array
                const int tl  = tid & 127;
                const int b   = tl >> 3;
                const int seg = tl & 7;
                const float* s;
                size_t rstr;
                if (arr == 0) {
                    if (layer == 0) { s = x + (size_t)t * HH; rstr = (size_t)TT * HH; }
                    else            { s = h1buf + (size_t)(t & 1) * BB * HH; rstr = HH; }
                } else {
                    if (t == 0) s = h0 + (size_t)layer * BB * HH;
                    else        s = hbuf_own + (size_t)((t - 1) & 1) * BB * HH;
                    rstr = HH;
                }
                const float* srow = s + (size_t)b * rstr + seg * 64;
                float* drow = act_lds + (arr * 16 + b) * PADW + seg * 64;
                #pragma unroll
                for (int q = 0; q < 16; ++q)
                    *(float4*)(drow + q * 4) = *(const float4*)(srow + q * 4);
            }
            __syncthreads();

            // ---- 4x4 register-tile dot over this thread's 64-wide k chunk ----
            float acc[4][4];
            #pragma unroll
            for (int i = 0; i < 4; ++i)
                #pragma unroll
                for (int j = 0; j < 4; ++j) acc[i][j] = 0.0f;

            const float* wb = w_lds   + (mat * 16 + rg * 4) * PADW + kc * 64;
            const float* ab = act_lds + (mat * 16 + bg * 4) * PADW + kc * 64;
            #pragma unroll
            for (int q = 0; q < 16; ++q) {
                const int idx = ((q + kc) & 15) << 2;   // kc-rotation: spreads banks
                float4 wv[4], av[4];
                #pragma unroll
                for (int i = 0; i < 4; ++i) wv[i] = *(const float4*)(wb + i * PADW + idx);
                #pragma unroll
                for (int j = 0; j < 4; ++j) av[j] = *(const float4*)(ab + j * PADW + idx);
                #pragma unroll
                for (int i = 0; i < 4; ++i)
                    #pragma unroll
                    for (int j = 0; j < 4; ++j)
                        acc[i][j] += wv[i].x * av[j].x + wv[i].y * av[j].y +
                                     wv[i].z * av[j].z + wv[i].w * av[j].w;
            }
            #pragma unroll
            for (int i = 0; i < 4; ++i)
                #pragma unroll
                for (int j = 0; j < 4; ++j)
                    partial[((rg * 4 + i) * 16 + (bg * 4 + j)) * 17 + (mat * 8 + kc)] = acc[i][j];
            __syncthreads();

            // ---- reduce 16 partials per (row,b) + bias ----
            {
                const int r = tid >> 4, b = tid & 15;
                const float* p = partial + (r * 16 + b) * 17;
                float s = bias_lds[r];
                #pragma unroll
                for (int q = 0; q < 16; ++q) s += p[q];
                gval[r * 16 + b] = s;
            }
            __syncthreads();

            // ---- gate nonlinearities + state update (64 threads: b x jj) ----
            if (tid < 64) {
                const int jj = tid & 3, b = tid >> 2;
                const float gi = gval[(0 + jj) * 16 + b];
                const float gf = gval[(4 + jj) * 16 + b];
                const float gg = gval[(8 + jj) * 16 + b];
                const float go = gval[(12 + jj) * 16 + b];
                const float i_ = 1.0f / (1.0f + __expf(-gi));
                const float f_ = 1.0f / (1.0f + __expf(-gf));
                const float g_ = tanhf(gg);
                const float o_ = 1.0f / (1.0f + __expf(-go));
                c_reg = f_ * c_reg + i_ * g_;
                const float h_ = o_ * tanhf(c_reg);
                hout[b * 4 + jj] = h_;
            }
            __syncthreads();

            // ---- store h (and final output) ----
            if (tid < 16) {
                const int b = tid;
                float4 hv = *(const float4*)(hout + b * 4);
                float* dst = hbuf_own + (size_t)(t & 1) * BB * HH + (size_t)b * HH + lw * 4;
                *(float4*)dst = hv;
                if (t == TT - 1) {
                    float* o = out + (size_t)layer * BB * HH + (size_t)b * HH + lw * 4;
                    *(float4*)o = hv;
                }
            }
        }
        grid.sync();   // device-scope fence: h(t) visible to all WGs for step t+1
    }
}

extern "C" void kernel_launch(void* const* d_in, const int* in_sizes, int n_in,
                              void* d_out, int out_size, void* d_ws, size_t ws_size,
                              hipStream_t stream) {
    const float* xp    = (const float*)d_in[0];
    const float* h0p   = (const float*)d_in[1];
    const float* c0p   = (const float*)d_in[2];
    const float* wih0  = (const float*)d_in[3];
    const float* whh0  = (const float*)d_in[4];
    const float* bih0  = (const float*)d_in[5];
    const float* bhh0  = (const float*)d_in[6];
    const float* wih1  = (const float*)d_in[7];
    const float* whh1  = (const float*)d_in[8];
    const float* bih1  = (const float*)d_in[9];
    const float* bhh1  = (const float*)d_in[10];
    float* outp  = (float*)d_out;
    float* h1buf = (float*)d_ws;                 // 2*16*512 floats
    float* h2buf = h1buf + 2 * BB * HH;          // 2*16*512 floats

    void* args[] = { &xp, &h0p, &c0p, &wih0, &whh0, &bih0, &bhh0,
                     &wih1, &whh1, &bih1, &bhh1, &outp, &h1buf, &h2buf };
    hipLaunchCooperativeKernel(lstm2_coop, dim3(256), dim3(256), args, 0, stream);
}

// Round 2
// 37678.757 us; speedup vs baseline: 1.0249x; 1.0249x over previous
//
#include <hip/hip_runtime.h>
#include <cstddef>
#include <cstdint>

#define BB 16
#define TT 1024
#define HH 512
#define R1 4   // h1 ring depth (layer-0 output)
#define R2 2   // h2 ring depth (layer-1 output)

typedef __attribute__((address_space(1))) const unsigned int GBUF;
typedef __attribute__((address_space(3))) unsigned int LBUF;

// Stage 16B/lane: per-lane global addr g (lane i reads g), LDS dest = uniform base + lane*16.
__device__ __forceinline__ void gl_lds16(const float* g, float* l) {
    __builtin_amdgcn_global_load_lds((GBUF*)g, (LBUF*)l, 16, 0, 0);
}

// 256 WGs x 256 threads, 1 WG/CU. WG: layer = wg>>7, lw = wg&127 owns h cols lw*4..+3.
// No grid.sync: ticket-based producer/consumer flow through ring buffers in d_ws.
__global__ __launch_bounds__(256, 1)
void lstm2_flow(const float* __restrict__ x,
                const float* __restrict__ h0,
                const float* __restrict__ c0,
                const float* __restrict__ w_ih0, const float* __restrict__ w_hh0,
                const float* __restrict__ b_ih0, const float* __restrict__ b_hh0,
                const float* __restrict__ w_ih1, const float* __restrict__ w_hh1,
                const float* __restrict__ b_ih1, const float* __restrict__ b_hh1,
                float* __restrict__ out,
                int*   __restrict__ tick,     // [256] zeroed by memset before launch
                float* __restrict__ h1ring,   // [R1][BB][HH]
                float* __restrict__ h2ring)   // [R2][BB][HH]
{
    __shared__ float act0[2 * BB * HH];   // layer input: x slots (L0, double-buffered) or h1 (L1)
    __shared__ float act1[BB * HH];       // own h(t-1)
    __shared__ float partial[16 * 16 * 17];
    __shared__ float gval[16 * 16];
    __shared__ float bias_lds[16];

    const int tid   = threadIdx.x;
    const int wg    = blockIdx.x;
    const int layer = wg >> 7;
    const int lw    = wg & 127;

    const float* w_in  = layer ? w_ih1 : w_ih0;
    const float* w_rec = layer ? w_hh1 : w_hh0;
    const float* b_in  = layer ? b_ih1 : b_ih0;
    const float* b_rec = layer ? b_hh1 : b_hh0;
    float* ring_own    = layer ? h2ring : h1ring;
    const int rmask    = layer ? (R2 - 1) : (R1 - 1);

    const int lane = tid & 63;
    const int wv   = tid >> 6;     // wave 0..3
    const int mat  = wv & 1;       // 0: input matrix, 1: recurrent matrix
    const int p    = wv >> 1;      // k half: [p*256, p*256+256)
    const int r    = lane & 15;    // gate-row r = gate*4 + jj
    const int kc   = lane >> 4;    // 0..3, interleaved k: k = p*256 + q*16 + kc*4 + u

    // ---- one-time: weights -> 64 VGPRs/thread (no LDS weight reads ever) ----
    float4 wreg[16];
    {
        const int gate = r >> 2, jj = r & 3;
        const int grow = gate * HH + lw * 4 + jj;
        const float* wsrc = (mat ? w_rec : w_in) + (size_t)grow * HH + p * 256 + kc * 4;
        #pragma unroll
        for (int q = 0; q < 16; ++q)
            wreg[q] = *(const float4*)(wsrc + q * 16);
    }
    if (tid < 16) {
        const int g2 = tid >> 2, j2 = tid & 3;
        const int gr = g2 * HH + lw * 4 + j2;
        bias_lds[tid] = b_in[gr] + b_rec[gr];
    }
    float c_reg = 0.f;
    if (tid < 64) {
        const int jj = tid & 3, b = tid >> 2;
        c_reg = c0[(size_t)layer * BB * HH + (size_t)b * HH + lw * 4 + jj];
    }
    __syncthreads();

    for (int t = 0; t < TT; ++t) {
        // ---- ticket poll (wave 0): wait for producers, and for ring-overwrite safety ----
        {
            // L0 step t: needs h1(t-1) -> minL1 >= t ; overwrites h1(t-4) -> minL2 >= t-3
            // L1 step t: needs h1(t)   -> minL1 >= t+1 ; needs h2(t-1) -> minL2 >= t
            const int needL1 = layer ? (t + 1) : t;
            const int needL2 = layer ? t       : (t - 3);
            if (tid < 64) {
                for (;;) {
                    int a0 = __hip_atomic_load(&tick[tid],       __ATOMIC_RELAXED, __HIP_MEMORY_SCOPE_AGENT);
                    int a1 = __hip_atomic_load(&tick[tid + 64],  __ATOMIC_RELAXED, __HIP_MEMORY_SCOPE_AGENT);
                    int a2 = __hip_atomic_load(&tick[tid + 128], __ATOMIC_RELAXED, __HIP_MEMORY_SCOPE_AGENT);
                    int a3 = __hip_atomic_load(&tick[tid + 192], __ATOMIC_RELAXED, __HIP_MEMORY_SCOPE_AGENT);
                    bool ok = (a0 >= needL1) && (a1 >= needL1) && (a2 >= needL2) && (a3 >= needL2);
                    if (__ballot(ok) == ~0ull) break;
                }
            }
            __syncthreads();
        }
        __threadfence();   // acquire side: invalidate L1/L2 so staged h reads are fresh

        // ---- stage activations into LDS via global_load_lds (16B/lane) ----
        {
            // act1 <- own h(t-1): 32 KB contiguous; each wave stages 8 KB
            const float* s1 = (t == 0) ? (h0 + (size_t)layer * BB * HH)
                                       : (ring_own + (size_t)((t - 1) & rmask) * BB * HH);
            {
                const float* g = s1 + (wv * 8) * 256 + lane * 4;
                float* l = act1 + (wv * 8) * 256;
                #pragma unroll
                for (int c2 = 0; c2 < 8; ++c2)
                    gl_lds16(g + c2 * 256, l + c2 * 256);
            }
            if (layer == 0) {
                if (t == 0) {   // stage x(0) into slot 0 now
                    #pragma unroll
                    for (int c2 = 0; c2 < 8; ++c2) {
                        const int ch = wv * 8 + c2, b = ch >> 1, hf = ch & 1;
                        const float* g = x + ((size_t)b * TT + 0) * HH + hf * 256 + lane * 4;
                        gl_lds16(g, act0 + b * HH + hf * 256);
                    }
                }
                if (t + 1 < TT) {   // prefetch x(t+1) into slot (t+1)&1 (drains at this sync)
                    float* l0 = act0 + ((t + 1) & 1) * BB * HH;
                    #pragma unroll
                    for (int c2 = 0; c2 < 8; ++c2) {
                        const int ch = wv * 8 + c2, b = ch >> 1, hf = ch & 1;
                        const float* g = x + ((size_t)b * TT + (t + 1)) * HH + hf * 256 + lane * 4;
                        gl_lds16(g, l0 + b * HH + hf * 256);
                    }
                }
            } else {
                // act0 slot t&1 <- h1(t): 32 KB contiguous
                const float* s0 = h1ring + (size_t)(t & (R1 - 1)) * BB * HH;
                float* l0 = act0 + (t & 1) * BB * HH;
                const float* g = s0 + (wv * 8) * 256 + lane * 4;
                float* l = l0 + (wv * 8) * 256;
                #pragma unroll
                for (int c2 = 0; c2 < 8; ++c2)
                    gl_lds16(g + c2 * 256, l + c2 * 256);
            }
        }
        __syncthreads();   // compiler drains vmcnt here -> staged LDS ready

        // ---- partial dots: weights from VGPRs, acts broadcast from LDS (conflict-free) ----
        {
            const float* abase = (mat == 0) ? (act0 + (t & 1) * BB * HH) : act1;
            const float* ab0 = abase + p * 256 + kc * 4;
            for (int b = 0; b < 16; ++b) {
                const float* ab = ab0 + (size_t)b * HH;
                float ax = 0.f, ay = 0.f, az = 0.f, aw = 0.f;
                #pragma unroll
                for (int q = 0; q < 16; ++q) {
                    float4 av = *(const float4*)(ab + q * 16);
                    ax += wreg[q].x * av.x;
                    ay += wreg[q].y * av.y;
                    az += wreg[q].z * av.z;
                    aw += wreg[q].w * av.w;
                }
                partial[(r * 16 + b) * 17 + (mat * 8 + p * 4 + kc)] = (ax + ay) + (az + aw);
            }
        }
        __syncthreads();

        // ---- reduce 16 partials + bias -> gate pre-activations ----
        {
            const int rr = tid >> 4, b = tid & 15;
            const float* pp = partial + (rr * 16 + b) * 17;
            float s = bias_lds[rr];
            #pragma unroll
            for (int q = 0; q < 16; ++q) s += pp[q];
            gval[rr * 16 + b] = s;
        }
        __syncthreads();

        // ---- gate nonlinearities + state update + publish h ----
        if (tid < 64) {
            const int jj = tid & 3, b = tid >> 2;
            const float gi = gval[(0  + jj) * 16 + b];
            const float gf = gval[(4  + jj) * 16 + b];
            const float gg = gval[(8  + jj) * 16 + b];
            const float go = gval[(12 + jj) * 16 + b];
            const float i_ = 1.f / (1.f + __expf(-gi));
            const float f_ = 1.f / (1.f + __expf(-gf));
            const float g_ = tanhf(gg);
            const float o_ = 1.f / (1.f + __expf(-go));
            c_reg = f_ * c_reg + i_ * g_;
            const float h_ = o_ * tanhf(c_reg);
            ring_own[(size_t)(t & rmask) * BB * HH + (size_t)b * HH + lw * 4 + jj] = h_;
            if (t == TT - 1)
                out[(size_t)layer * BB * HH + (size_t)b * HH + lw * 4 + jj] = h_;
            __threadfence();   // release side: make h visible device-wide before ticket
        }
        __syncthreads();
        if (tid == 0)
            __hip_atomic_store(&tick[wg], t + 1, __ATOMIC_RELEASE, __HIP_MEMORY_SCOPE_AGENT);
    }
}

extern "C" void kernel_launch(void* const* d_in, const int* in_sizes, int n_in,
                              void* d_out, int out_size, void* d_ws, size_t ws_size,
                              hipStream_t stream) {
    const float* xp   = (const float*)d_in[0];
    const float* h0p  = (const float*)d_in[1];
    const float* c0p  = (const float*)d_in[2];
    const float* wih0 = (const float*)d_in[3];
    const float* whh0 = (const float*)d_in[4];
    const float* bih0 = (const float*)d_in[5];
    const float* bhh0 = (const float*)d_in[6];
    const float* wih1 = (const float*)d_in[7];
    const float* whh1 = (const float*)d_in[8];
    const float* bih1 = (const float*)d_in[9];
    const float* bhh1 = (const float*)d_in[10];
    float* outp = (float*)d_out;

    int*   tick   = (int*)d_ws;
    float* base   = (float*)d_ws;
    float* h1ring = base + 1024;                  // 4 KB offset
    float* h2ring = h1ring + R1 * BB * HH;        // +128 KB
    // total ws use: 4 KB + 128 KB + 64 KB = 196 KB

    hipMemsetAsync(d_ws, 0, 4096, stream);        // zero tickets (graph-capture safe)

    void* args[] = { &xp, &h0p, &c0p, &wih0, &whh0, &bih0, &bhh0,
                     &wih1, &whh1, &bih1, &bhh1, &outp, &tick, &h1ring, &h2ring };
    hipLaunchCooperativeKernel(lstm2_flow, dim3(256), dim3(256), args, 0, stream);
}

// Round 3
// 17735.542 us; speedup vs baseline: 2.1775x; 2.1245x over previous
//
#include <hip/hip_runtime.h>
#include <cstddef>
#include <cstdint>

#define BB 16
#define TT 1024
#define HH 512
#define R1SLOTS 4   // h1 ring depth
#define R2SLOTS 2   // h2 ring depth

typedef __attribute__((address_space(1))) const unsigned int GBUF;
typedef __attribute__((address_space(3))) unsigned int LBUF;

__device__ __forceinline__ void gl_lds16(const float* g, float* l) {
    __builtin_amdgcn_global_load_lds((GBUF*)g, (LBUF*)l, 16, 0, 0);
}

__device__ __forceinline__ void wait_ge(const int* p, int v) {
    while (__hip_atomic_load(p, __ATOMIC_RELAXED, __HIP_MEMORY_SCOPE_AGENT) < v) {
        __builtin_amdgcn_s_sleep(1);
    }
}

// 256 WGs x 256 threads, 1 WG/CU. layer = wg>>7, lw = wg&127 owns h cols lw*4..+3.
// Producer/consumer flow via per-timestep counters; agent-scope atomics only
// (sc1 path, LLC coherence point) — no wbl2-class fences anywhere.
__global__ __launch_bounds__(256, 1)
void lstm2_flow3(const float* __restrict__ x,
                 const float* __restrict__ h0,
                 const float* __restrict__ c0,
                 const float* __restrict__ w_ih0, const float* __restrict__ w_hh0,
                 const float* __restrict__ b_ih0, const float* __restrict__ b_hh0,
                 const float* __restrict__ w_ih1, const float* __restrict__ w_hh1,
                 const float* __restrict__ b_ih1, const float* __restrict__ b_hh1,
                 float* __restrict__ out,
                 int*   __restrict__ cntL0,    // [TT], zeroed pre-launch
                 int*   __restrict__ cntL1,    // [TT], zeroed pre-launch
                 float* __restrict__ h1ring,   // [R1SLOTS][BB][HH]
                 float* __restrict__ h2ring)   // [R2SLOTS][BB][HH]
{
    __shared__ float act0[2 * BB * HH];   // L0: x(t) double-buffered; L1: h1(t) in slot 0
    __shared__ float act1[BB * HH];       // own h(t-1)
    __shared__ float partial[16 * 16 * 17];
    __shared__ float gval[16 * 16];
    __shared__ float bias_lds[16];

    const int tid   = threadIdx.x;
    const int wg    = blockIdx.x;
    const int layer = wg >> 7;
    const int lw    = wg & 127;

    const float* w_in  = layer ? w_ih1 : w_ih0;
    const float* w_rec = layer ? w_hh1 : w_hh0;
    const float* b_in  = layer ? b_ih1 : b_ih0;
    const float* b_rec = layer ? b_hh1 : b_hh0;
    float* ring_own    = layer ? h2ring : h1ring;
    int*   cnt_own     = layer ? cntL1 : cntL0;
    const int rmask    = layer ? (R2SLOTS - 1) : (R1SLOTS - 1);

    const int lane = tid & 63;
    const int wv   = tid >> 6;     // 0..3
    const int mat  = wv & 1;       // 0: input matrix, 1: recurrent matrix
    const int p    = wv >> 1;      // k half
    const int r    = lane & 15;    // gate-row r = gate*4 + jj
    const int kc   = lane >> 4;    // 0..3

    // ---- one-time: weights -> 64 VGPRs/thread ----
    float4 wreg[16];
    {
        const int gate = r >> 2, jj = r & 3;
        const int grow = gate * HH + lw * 4 + jj;
        const float* wsrc = (mat ? w_rec : w_in) + (size_t)grow * HH + p * 256 + kc * 4;
        #pragma unroll
        for (int q = 0; q < 16; ++q)
            wreg[q] = *(const float4*)(wsrc + q * 16);
    }
    if (tid < 16) {
        const int g2 = tid >> 2, j2 = tid & 3;
        const int gr = g2 * HH + lw * 4 + j2;
        bias_lds[tid] = b_in[gr] + b_rec[gr];
    }
    float c_reg = 0.f;
    if (tid < 64) {
        const int jj = tid & 3, b = tid >> 2;
        c_reg = c0[(size_t)layer * BB * HH + (size_t)b * HH + lw * 4 + jj];
    }
    // pre-stage x(0) (L0, input waves): each wave stages its own k-columns of all b rows
    if (layer == 0 && mat == 0) {
        #pragma unroll
        for (int b = 0; b < 16; ++b)
            gl_lds16(x + ((size_t)b * TT) * HH + p * 256 + lane * 4,
                     act0 + b * HH + p * 256);
    }
    __syncthreads();

    auto compute_half = [&](const float* abase) {
        const float* ab0 = abase + p * 256 + kc * 4;
        for (int b = 0; b < 16; ++b) {
            const float* ab = ab0 + (size_t)b * HH;
            float ax = 0.f, ay = 0.f, az = 0.f, aw = 0.f;
            #pragma unroll
            for (int q = 0; q < 16; ++q) {
                float4 av = *(const float4*)(ab + q * 16);
                ax += wreg[q].x * av.x;
                ay += wreg[q].y * av.y;
                az += wreg[q].z * av.z;
                aw += wreg[q].w * av.w;
            }
            partial[(r * 16 + b) * 17 + (mat * 8 + p * 4 + kc)] = (ax + ay) + (az + aw);
        }
    };

    for (int t = 0; t < TT; ++t) {
        // ======== phase A: per-wave specialized (no cross-wave deps) ========
        if (mat == 0) {
            if (layer == 1) {
                wait_ge(&cntL0[t], 128);                       // h1(t) published
                __builtin_amdgcn_fence(__ATOMIC_ACQUIRE, "agent");  // buffer_inv only
                const float* s0 = h1ring + (size_t)(t & (R1SLOTS - 1)) * BB * HH;
                #pragma unroll
                for (int b = 0; b < 16; ++b)
                    gl_lds16(s0 + (size_t)b * HH + p * 256 + lane * 4,
                             act0 + b * HH + p * 256);
            }
            asm volatile("s_waitcnt vmcnt(0)" ::: "memory");   // own staged data ready
            compute_half(act0 + ((layer == 0) ? (t & 1) * BB * HH : 0));
            if (layer == 0 && t + 1 < TT) {                    // prefetch x(t+1)
                float* l0 = act0 + ((t + 1) & 1) * BB * HH;
                #pragma unroll
                for (int b = 0; b < 16; ++b)
                    gl_lds16(x + ((size_t)b * TT + (t + 1)) * HH + p * 256 + lane * 4,
                             l0 + b * HH + p * 256);
            }
        } else {
            if (t == 0) {
                const float* s1 = h0 + (size_t)layer * BB * HH;
                #pragma unroll
                for (int b = 0; b < 16; ++b)
                    gl_lds16(s1 + (size_t)b * HH + p * 256 + lane * 4,
                             act1 + b * HH + p * 256);
            } else {
                if (layer == 0) {
                    wait_ge(&cntL0[t - 1], 128);               // h1(t-1) published
                    if (t >= R1SLOTS) wait_ge(&cntL1[t - R1SLOTS], 128);  // ring safety
                } else {
                    wait_ge(&cntL1[t - 1], 128);               // h2(t-1) published
                }
                __builtin_amdgcn_fence(__ATOMIC_ACQUIRE, "agent");
                const float* s1 = ring_own + (size_t)((t - 1) & rmask) * BB * HH;
                #pragma unroll
                for (int b = 0; b < 16; ++b)
                    gl_lds16(s1 + (size_t)b * HH + p * 256 + lane * 4,
                             act1 + b * HH + p * 256);
            }
            asm volatile("s_waitcnt vmcnt(0)" ::: "memory");
            compute_half(act1);
        }
        __syncthreads();

        // ======== phase B: reduce + gates + publish ========
        {
            const int rr = tid >> 4, b = tid & 15;
            const float* pp = partial + (rr * 16 + b) * 17;
            float s = bias_lds[rr];
            #pragma unroll
            for (int q = 0; q < 16; ++q) s += pp[q];
            gval[rr * 16 + b] = s;
        }
        __syncthreads();

        if (tid < 64) {
            const int jj = tid & 3, b = tid >> 2;
            const float gi = gval[(0  + jj) * 16 + b];
            const float gf = gval[(4  + jj) * 16 + b];
            const float gg = gval[(8  + jj) * 16 + b];
            const float go = gval[(12 + jj) * 16 + b];
            const float i_ = 1.f / (1.f + __expf(-gi));
            const float f_ = 1.f / (1.f + __expf(-gf));
            const float g_ = tanhf(gg);
            const float o_ = 1.f / (1.f + __expf(-go));
            c_reg = f_ * c_reg + i_ * g_;
            const float h_ = o_ * tanhf(c_reg);
            // publish: agent-scope relaxed store -> LLC (sc1), no fence
            float* dst = ring_own + (size_t)(t & rmask) * BB * HH + (size_t)b * HH + lw * 4 + jj;
            __hip_atomic_store(dst, h_, __ATOMIC_RELAXED, __HIP_MEMORY_SCOPE_AGENT);
            if (t == TT - 1)
                out[(size_t)layer * BB * HH + (size_t)b * HH + lw * 4 + jj] = h_;
        }
        // hand-built release: wave0's stores drained, then counter bump
        asm volatile("s_waitcnt vmcnt(0)" ::: "memory");
        if (tid == 0)
            __hip_atomic_fetch_add(&cnt_own[t], 1, __ATOMIC_RELAXED, __HIP_MEMORY_SCOPE_AGENT);
        __syncthreads();
    }
}

extern "C" void kernel_launch(void* const* d_in, const int* in_sizes, int n_in,
                              void* d_out, int out_size, void* d_ws, size_t ws_size,
                              hipStream_t stream) {
    const float* xp   = (const float*)d_in[0];
    const float* h0p  = (const float*)d_in[1];
    const float* c0p  = (const float*)d_in[2];
    const float* wih0 = (const float*)d_in[3];
    const float* whh0 = (const float*)d_in[4];
    const float* bih0 = (const float*)d_in[5];
    const float* bhh0 = (const float*)d_in[6];
    const float* wih1 = (const float*)d_in[7];
    const float* whh1 = (const float*)d_in[8];
    const float* bih1 = (const float*)d_in[9];
    const float* bhh1 = (const float*)d_in[10];
    float* outp = (float*)d_out;

    int*   cntL0  = (int*)d_ws;                       // [1024]
    int*   cntL1  = cntL0 + TT;                       // [1024]
    float* h1ring = (float*)d_ws + 2 * TT;            // 128 KB
    float* h2ring = h1ring + R1SLOTS * BB * HH;       // 64 KB

    hipMemsetAsync(d_ws, 0, 2 * TT * sizeof(int), stream);   // zero counters

    void* args[] = { &xp, &h0p, &c0p, &wih0, &whh0, &bih0, &bhh0,
                     &wih1, &whh1, &bih1, &bhh1, &outp, &cntL0, &cntL1, &h1ring, &h2ring };
    hipLaunchCooperativeKernel(lstm2_flow3, dim3(256), dim3(256), args, 0, stream);
}

// Round 5
// 15898.344 us; speedup vs baseline: 2.4291x; 1.1156x over previous
//
#include <hip/hip_runtime.h>
#include <cstddef>
#include <cstdint>

#define BB 16
#define TT 1024
#define HH 512
#define R1S 4   // h1 ring slots
#define R2S 2   // h2 ring slots

typedef __attribute__((address_space(1))) const unsigned int GBUF;
typedef __attribute__((address_space(3))) unsigned int LBUF;

// async global->LDS, 16 B/lane; LDS dst = wave-uniform base + lane*16
__device__ __forceinline__ void gl_lds16(const float* g, float* l) {
    __builtin_amdgcn_global_load_lds((GBUF*)g, (LBUF*)l, 16, 0, 0);
}

// ballot-poll one 128-flag bank: wait until flags[base..base+127] all >= need
__device__ __forceinline__ void poll_bank(const int* flags, int base, int need) {
    const int lane = threadIdx.x & 63;
    for (;;) {
        int a = __hip_atomic_load(&flags[base + lane],      __ATOMIC_RELAXED, __HIP_MEMORY_SCOPE_AGENT);
        int b = __hip_atomic_load(&flags[base + lane + 64], __ATOMIC_RELAXED, __HIP_MEMORY_SCOPE_AGENT);
        if (__ballot((a >= need) && (b >= need)) == ~0ull) break;
        __builtin_amdgcn_s_sleep(1);
    }
}

// 256 WGs x 256 threads, 1 WG/CU. layer = wg>>7, lw = wg&127 owns h cols lw*4..+3.
// R3's proven skeleton; sync via per-WG flag stores (no atomic RMW hot line).
__global__ __launch_bounds__(256, 1)
void lstm2_flow5(const float* __restrict__ x,
                 const float* __restrict__ h0,
                 const float* __restrict__ c0,
                 const float* __restrict__ w_ih0, const float* __restrict__ w_hh0,
                 const float* __restrict__ b_ih0, const float* __restrict__ b_hh0,
                 const float* __restrict__ w_ih1, const float* __restrict__ w_hh1,
                 const float* __restrict__ b_ih1, const float* __restrict__ b_hh1,
                 float* __restrict__ out,
                 int*   __restrict__ flags,    // [256] zeroed pre-launch; [0..127]=L0, [128..255]=L1
                 float* __restrict__ h1ring,   // [R1S][BB][HH]
                 float* __restrict__ h2ring)   // [R2S][BB][HH]
{
    __shared__ float act0[2 * BB * HH];   // L0: x(t) double-buffered; L1: h1(t) in slot 0
    __shared__ float act1[BB * HH];       // own h(t-1)
    __shared__ float partial[16 * 16 * 17];
    __shared__ float gval[16 * 16];
    __shared__ float bias_lds[16];

    const int tid   = threadIdx.x;
    const int wg    = blockIdx.x;
    const int layer = wg >> 7;
    const int lw    = wg & 127;

    const float* w_in  = layer ? w_ih1 : w_ih0;
    const float* w_rec = layer ? w_hh1 : w_hh0;
    const float* b_in  = layer ? b_ih1 : b_ih0;
    const float* b_rec = layer ? b_hh1 : b_hh0;
    float* ring_own    = layer ? h2ring : h1ring;
    const int rmask    = layer ? (R2S - 1) : (R1S - 1);

    const int lane = tid & 63;
    const int wv   = tid >> 6;     // 0..3
    const int mat  = wv & 1;       // 0: input matrix, 1: recurrent matrix
    const int p    = wv >> 1;      // k half
    const int r    = lane & 15;    // gate-row r = gate*4 + jj
    const int kc   = lane >> 4;    // 0..3

    // ---- one-time: weights -> 64 VGPRs/thread ----
    float4 wreg[16];
    {
        const int gate = r >> 2, jj = r & 3;
        const int grow = gate * HH + lw * 4 + jj;
        const float* wsrc = (mat ? w_rec : w_in) + (size_t)grow * HH + p * 256 + kc * 4;
        #pragma unroll
        for (int q = 0; q < 16; ++q)
            wreg[q] = *(const float4*)(wsrc + q * 16);
    }
    if (tid < 16) {
        const int g2 = tid >> 2, j2 = tid & 3;
        const int gr = g2 * HH + lw * 4 + j2;
        bias_lds[tid] = b_in[gr] + b_rec[gr];
    }
    float c_reg = 0.f;
    if (tid < 64) {
        const int jj = tid & 3, b = tid >> 2;
        c_reg = c0[(size_t)layer * BB * HH + (size_t)b * HH + lw * 4 + jj];
    }
    // pre-stage x(0) (L0, input waves): each wave stages its own k-columns of all b rows
    if (layer == 0 && mat == 0) {
        #pragma unroll
        for (int b = 0; b < 16; ++b)
            gl_lds16(x + ((size_t)b * TT) * HH + p * 256 + lane * 4,
                     act0 + b * HH + p * 256);
    }
    __syncthreads();

    auto compute_half = [&](const float* abase) {
        const float* ab0 = abase + p * 256 + kc * 4;
        for (int b = 0; b < 16; ++b) {
            const float* ab = ab0 + (size_t)b * HH;
            float ax = 0.f, ay = 0.f, az = 0.f, aw = 0.f;
            #pragma unroll
            for (int q = 0; q < 16; ++q) {
                float4 av = *(const float4*)(ab + q * 16);
                ax += wreg[q].x * av.x;
                ay += wreg[q].y * av.y;
                az += wreg[q].z * av.z;
                aw += wreg[q].w * av.w;
            }
            partial[(r * 16 + b) * 17 + (mat * 8 + p * 4 + kc)] = (ax + ay) + (az + aw);
        }
    };

    for (int t = 0; t < TT; ++t) {
        // ======== phase A: per-wave specialized (no cross-wave deps) ========
        if (mat == 0) {
            if (layer == 1) {
                poll_bank(flags, 0, t + 1);                    // h1(t) published by all L0
                __builtin_amdgcn_fence(__ATOMIC_ACQUIRE, "agent");  // inv only, no wb
                const float* s0 = h1ring + (size_t)(t & (R1S - 1)) * BB * HH;
                #pragma unroll
                for (int b = 0; b < 16; ++b)
                    gl_lds16(s0 + (size_t)b * HH + p * 256 + lane * 4,
                             act0 + b * HH + p * 256);
            }
            asm volatile("s_waitcnt vmcnt(0)" ::: "memory");   // own staged data ready
            compute_half(act0 + ((layer == 0) ? (t & 1) * BB * HH : 0));
            // x(t+1) prefetch moved to after the flag publish (off the release path)
        } else {
            if (t == 0) {
                const float* s1 = h0 + (size_t)layer * BB * HH;
                #pragma unroll
                for (int b = 0; b < 16; ++b)
                    gl_lds16(s1 + (size_t)b * HH + p * 256 + lane * 4,
                             act1 + b * HH + p * 256);
            } else {
                if (layer == 0) {
                    poll_bank(flags, 0, t);                    // h1(t-1) published
                    if (t >= R1S) poll_bank(flags, 128, t - (R1S - 1));  // ring safety
                } else {
                    poll_bank(flags, 128, t);                  // h2(t-1) published
                }
                __builtin_amdgcn_fence(__ATOMIC_ACQUIRE, "agent");
                const float* s1 = ring_own + (size_t)((t - 1) & rmask) * BB * HH;
                #pragma unroll
                for (int b = 0; b < 16; ++b)
                    gl_lds16(s1 + (size_t)b * HH + p * 256 + lane * 4,
                             act1 + b * HH + p * 256);
            }
            asm volatile("s_waitcnt vmcnt(0)" ::: "memory");
            compute_half(act1);
        }
        __syncthreads();

        // ======== phase B: reduce + gates + publish ========
        {
            const int rr = tid >> 4, b = tid & 15;
            const float* pp = partial + (rr * 16 + b) * 17;
            float s = bias_lds[rr];
            #pragma unroll
            for (int q = 0; q < 16; ++q) s += pp[q];
            gval[rr * 16 + b] = s;
        }
        __syncthreads();

        if (tid < 64) {
            const int jj = tid & 3, b = tid >> 2;
            const float gi = gval[(0  + jj) * 16 + b];
            const float gf = gval[(4  + jj) * 16 + b];
            const float gg = gval[(8  + jj) * 16 + b];
            const float go = gval[(12 + jj) * 16 + b];
            const float i_ = 1.f / (1.f + __expf(-gi));
            const float f_ = 1.f / (1.f + __expf(-gf));
            const float g_ = tanhf(gg);
            const float o_ = 1.f / (1.f + __expf(-go));
            c_reg = f_ * c_reg + i_ * g_;
            const float h_ = o_ * tanhf(c_reg);
            // publish: agent-scope relaxed store -> LLC (sc1), no cache-maintenance fence
            float* dst = ring_own + (size_t)(t & rmask) * BB * HH + (size_t)b * HH + lw * 4 + jj;
            __hip_atomic_store(dst, h_, __ATOMIC_RELAXED, __HIP_MEMORY_SCOPE_AGENT);
            if (t == TT - 1)
                out[(size_t)layer * BB * HH + (size_t)b * HH + lw * 4 + jj] = h_;
        }
        // hand-built release: wave0's h stores drained at coherence point, then flag store
        asm volatile("s_waitcnt vmcnt(0)" ::: "memory");
        if (tid == 0)
            __hip_atomic_store(&flags[wg], t + 1, __ATOMIC_RELAXED, __HIP_MEMORY_SCOPE_AGENT);
        // x(t+1) prefetch AFTER the publish: drains at the loop-end barrier, not on the
        // release path. Same wave writes/reads its own act0 slot -> program-order safe.
        if (layer == 0 && mat == 0 && t + 1 < TT) {
            float* l0 = act0 + ((t + 1) & 1) * BB * HH;
            #pragma unroll
            for (int b = 0; b < 16; ++b)
                gl_lds16(x + ((size_t)b * TT + (t + 1)) * HH + p * 256 + lane * 4,
                         l0 + b * HH + p * 256);
        }
        __syncthreads();
    }
}

extern "C" void kernel_launch(void* const* d_in, const int* in_sizes, int n_in,
                              void* d_out, int out_size, void* d_ws, size_t ws_size,
                              hipStream_t stream) {
    const float* xp   = (const float*)d_in[0];
    const float* h0p  = (const float*)d_in[1];
    const float* c0p  = (const float*)d_in[2];
    const float* wih0 = (const float*)d_in[3];
    const float* whh0 = (const float*)d_in[4];
    const float* bih0 = (const float*)d_in[5];
    const float* bhh0 = (const float*)d_in[6];
    const float* wih1 = (const float*)d_in[7];
    const float* whh1 = (const float*)d_in[8];
    const float* bih1 = (const float*)d_in[9];
    const float* bhh1 = (const float*)d_in[10];
    float* outp = (float*)d_out;

    int*   flags  = (int*)d_ws;                        // [256]
    float* h1ring = (float*)d_ws + 1024;               // 4 KB offset; 128 KB
    float* h2ring = h1ring + R1S * BB * HH;            // 64 KB

    hipMemsetAsync(d_ws, 0, 4096, stream);             // zero flags

    void* args[] = { &xp, &h0p, &c0p, &wih0, &whh0, &bih0, &bhh0,
                     &wih1, &whh1, &bih1, &bhh1, &outp, &flags, &h1ring, &h2ring };
    hipLaunchCooperativeKernel(lstm2_flow5, dim3(256), dim3(256), args, 0, stream);
}

// Round 6
// 10002.959 us; speedup vs baseline: 3.8607x; 1.5894x over previous
//
#include <hip/hip_runtime.h>
#include <cstddef>
#include <cstdint>

#define BB 16
#define TT 1024
#define HH 512
#define R1S 4   // h1 ring slots
#define R2S 2   // h2 ring slots

typedef __attribute__((address_space(1))) const unsigned int GBUF;
typedef __attribute__((address_space(3))) unsigned int LBUF;

// async global->LDS, 16 B/lane; LDS dst = wave-uniform base + lane*16 (x / h0 only)
__device__ __forceinline__ void gl_lds16(const float* g, float* l) {
    __builtin_amdgcn_global_load_lds((GBUF*)g, (LBUF*)l, 16, 0, 0);
}

// ballot-poll one 128-flag bank: wait until flags[base..base+127] all >= need
__device__ __forceinline__ void poll_bank(const int* flags, int base, int need) {
    const int lane = threadIdx.x & 63;
    for (;;) {
        int a = __hip_atomic_load(&flags[base + lane],      __ATOMIC_RELAXED, __HIP_MEMORY_SCOPE_AGENT);
        int b = __hip_atomic_load(&flags[base + lane + 64], __ATOMIC_RELAXED, __HIP_MEMORY_SCOPE_AGENT);
        if (__ballot((a >= need) && (b >= need)) == ~0ull) break;
        __builtin_amdgcn_s_sleep(1);
    }
}

// Stage one 256-float k-half of all 16 rows (16 KB) from an agent-coherent ring:
// sc1 loads (bypass non-coherent per-XCD L2, read at LLC) -> VGPRs -> ds_write_b128.
// Own-wave stages, own-wave reads: in-wave vmcnt/program-order LDS suffice. No fences.
__device__ __forceinline__ void stage_half_sc1(const float* src, float* dstlds,
                                               int p, int lane) {
    const float* g = src   + p * 256 + lane * 4;
    float*       l = dstlds + p * 256 + lane * 4;
    float4 v[16];
    #pragma unroll
    for (int b = 0; b < 16; ++b) {
        const float* gp = g + (size_t)b * HH;
        asm volatile("global_load_dwordx4 %0, %1, off sc1"
                     : "=v"(v[b]) : "v"(gp));
    }
    asm volatile("s_waitcnt vmcnt(0)" ::: "memory");
    #pragma unroll
    for (int b = 0; b < 16; ++b)
        *(float4*)(l + (size_t)b * HH) = v[b];
}

// 256 WGs x 256 threads, 1 WG/CU. layer = wg>>7, lw = wg&127 owns h cols lw*4..+3.
// R5 skeleton; ring staging via sc1 loads, per-step acquire fences removed.
__global__ __launch_bounds__(256, 1)
void lstm2_flow6(const float* __restrict__ x,
                 const float* __restrict__ h0,
                 const float* __restrict__ c0,
                 const float* __restrict__ w_ih0, const float* __restrict__ w_hh0,
                 const float* __restrict__ b_ih0, const float* __restrict__ b_hh0,
                 const float* __restrict__ w_ih1, const float* __restrict__ w_hh1,
                 const float* __restrict__ b_ih1, const float* __restrict__ b_hh1,
                 float* __restrict__ out,
                 int*   __restrict__ flags,    // [256] zeroed pre-launch; [0..127]=L0, [128..255]=L1
                 float* __restrict__ h1ring,   // [R1S][BB][HH]
                 float* __restrict__ h2ring)   // [R2S][BB][HH]
{
    __shared__ float act0[2 * BB * HH];   // L0: x(t) double-buffered; L1: h1(t) in slot 0
    __shared__ float act1[BB * HH];       // own h(t-1)
    __shared__ float partial[16 * 16 * 17];
    __shared__ float gval[16 * 16];
    __shared__ float bias_lds[16];

    const int tid   = threadIdx.x;
    const int wg    = blockIdx.x;
    const int layer = wg >> 7;
    const int lw    = wg & 127;

    const float* w_in  = layer ? w_ih1 : w_ih0;
    const float* w_rec = layer ? w_hh1 : w_hh0;
    const float* b_in  = layer ? b_ih1 : b_ih0;
    const float* b_rec = layer ? b_hh1 : b_hh0;
    float* ring_own    = layer ? h2ring : h1ring;
    const int rmask    = layer ? (R2S - 1) : (R1S - 1);

    const int lane = tid & 63;
    const int wv   = tid >> 6;     // 0..3
    const int mat  = wv & 1;       // 0: input matrix, 1: recurrent matrix
    const int p    = wv >> 1;      // k half
    const int r    = lane & 15;    // gate-row r = gate*4 + jj
    const int kc   = lane >> 4;    // 0..3

    // ---- one-time: weights -> 64 VGPRs/thread ----
    float4 wreg[16];
    {
        const int gate = r >> 2, jj = r & 3;
        const int grow = gate * HH + lw * 4 + jj;
        const float* wsrc = (mat ? w_rec : w_in) + (size_t)grow * HH + p * 256 + kc * 4;
        #pragma unroll
        for (int q = 0; q < 16; ++q)
            wreg[q] = *(const float4*)(wsrc + q * 16);
    }
    if (tid < 16) {
        const int g2 = tid >> 2, j2 = tid & 3;
        const int gr = g2 * HH + lw * 4 + j2;
        bias_lds[tid] = b_in[gr] + b_rec[gr];
    }
    float c_reg = 0.f;
    if (tid < 64) {
        const int jj = tid & 3, b = tid >> 2;
        c_reg = c0[(size_t)layer * BB * HH + (size_t)b * HH + lw * 4 + jj];
    }
    // pre-stage x(0) (L0, input waves): each wave stages its own k-columns of all b rows
    if (layer == 0 && mat == 0) {
        #pragma unroll
        for (int b = 0; b < 16; ++b)
            gl_lds16(x + ((size_t)b * TT) * HH + p * 256 + lane * 4,
                     act0 + b * HH + p * 256);
    }
    __syncthreads();

    auto compute_half = [&](const float* abase) {
        const float* ab0 = abase + p * 256 + kc * 4;
        for (int b = 0; b < 16; ++b) {
            const float* ab = ab0 + (size_t)b * HH;
            float ax = 0.f, ay = 0.f, az = 0.f, aw = 0.f;
            #pragma unroll
            for (int q = 0; q < 16; ++q) {
                float4 av = *(const float4*)(ab + q * 16);
                ax += wreg[q].x * av.x;
                ay += wreg[q].y * av.y;
                az += wreg[q].z * av.z;
                aw += wreg[q].w * av.w;
            }
            partial[(r * 16 + b) * 17 + (mat * 8 + p * 4 + kc)] = (ax + ay) + (az + aw);
        }
    };

    for (int t = 0; t < TT; ++t) {
        // ======== phase A: per-wave specialized (no cross-wave deps) ========
        if (mat == 0) {
            if (layer == 1) {
                poll_bank(flags, 0, t + 1);                    // h1(t) published by all L0
                // no acquire fence: sc1 staging loads read at the LLC coherence point
                const float* s0 = h1ring + (size_t)(t & (R1S - 1)) * BB * HH;
                stage_half_sc1(s0, act0, p, lane);
            }
            asm volatile("s_waitcnt vmcnt(0)" ::: "memory");   // x prefetch (L0) staged
            compute_half(act0 + ((layer == 0) ? (t & 1) * BB * HH : 0));
        } else {
            if (t == 0) {
                const float* s1 = h0 + (size_t)layer * BB * HH;
                #pragma unroll
                for (int b = 0; b < 16; ++b)
                    gl_lds16(s1 + (size_t)b * HH + p * 256 + lane * 4,
                             act1 + b * HH + p * 256);
                asm volatile("s_waitcnt vmcnt(0)" ::: "memory");
            } else {
                if (layer == 0) {
                    poll_bank(flags, 0, t);                    // h1(t-1) published
                    if (t >= R1S) poll_bank(flags, 128, t - (R1S - 1));  // ring safety
                } else {
                    poll_bank(flags, 128, t);                  // h2(t-1) published
                }
                // no acquire fence: sc1 staging below
                const float* s1 = ring_own + (size_t)((t - 1) & rmask) * BB * HH;
                stage_half_sc1(s1, act1, p, lane);
            }
            compute_half(act1);
        }
        __syncthreads();

        // ======== phase B: reduce + gates + publish ========
        {
            const int rr = tid >> 4, b = tid & 15;
            const float* pp = partial + (rr * 16 + b) * 17;
            float s = bias_lds[rr];
            #pragma unroll
            for (int q = 0; q < 16; ++q) s += pp[q];
            gval[rr * 16 + b] = s;
        }
        __syncthreads();

        if (tid < 64) {
            const int jj = tid & 3, b = tid >> 2;
            const float gi = gval[(0  + jj) * 16 + b];
            const float gf = gval[(4  + jj) * 16 + b];
            const float gg = gval[(8  + jj) * 16 + b];
            const float go = gval[(12 + jj) * 16 + b];
            const float i_ = 1.f / (1.f + __expf(-gi));
            const float f_ = 1.f / (1.f + __expf(-gf));
            const float g_ = tanhf(gg);
            const float o_ = 1.f / (1.f + __expf(-go));
            c_reg = f_ * c_reg + i_ * g_;
            const float h_ = o_ * tanhf(c_reg);
            // publish: agent-scope relaxed store -> sc1 write-through at LLC
            float* dst = ring_own + (size_t)(t & rmask) * BB * HH + (size_t)b * HH + lw * 4 + jj;
            __hip_atomic_store(dst, h_, __ATOMIC_RELAXED, __HIP_MEMORY_SCOPE_AGENT);
            if (t == TT - 1)
                out[(size_t)layer * BB * HH + (size_t)b * HH + lw * 4 + jj] = h_;
        }
        // hand-built release: wave0's h stores complete at LLC, then flag store
        asm volatile("s_waitcnt vmcnt(0)" ::: "memory");
        if (tid == 0)
            __hip_atomic_store(&flags[wg], t + 1, __ATOMIC_RELAXED, __HIP_MEMORY_SCOPE_AGENT);
        // x(t+1) prefetch AFTER the publish (off the release path); same wave
        // writes/reads its own act0 slot -> program-order safe.
        if (layer == 0 && mat == 0 && t + 1 < TT) {
            float* l0 = act0 + ((t + 1) & 1) * BB * HH;
            #pragma unroll
            for (int b = 0; b < 16; ++b)
                gl_lds16(x + ((size_t)b * TT + (t + 1)) * HH + p * 256 + lane * 4,
                         l0 + b * HH + p * 256);
        }
        __syncthreads();
    }
}

extern "C" void kernel_launch(void* const* d_in, const int* in_sizes, int n_in,
                              void* d_out, int out_size, void* d_ws, size_t ws_size,
                              hipStream_t stream) {
    const float* xp   = (const float*)d_in[0];
    const float* h0p  = (const float*)d_in[1];
    const float* c0p  = (const float*)d_in[2];
    const float* wih0 = (const float*)d_in[3];
    const float* whh0 = (const float*)d_in[4];
    const float* bih0 = (const float*)d_in[5];
    const float* bhh0 = (const float*)d_in[6];
    const float* wih1 = (const float*)d_in[7];
    const float* whh1 = (const float*)d_in[8];
    const float* bih1 = (const float*)d_in[9];
    const float* bhh1 = (const float*)d_in[10];
    float* outp = (float*)d_out;

    int*   flags  = (int*)d_ws;                        // [256]
    float* h1ring = (float*)d_ws + 1024;               // 4 KB offset; 128 KB
    float* h2ring = h1ring + R1S * BB * HH;            // 64 KB

    hipMemsetAsync(d_ws, 0, 4096, stream);             // zero flags

    void* args[] = { &xp, &h0p, &c0p, &wih0, &whh0, &bih0, &bhh0,
                     &wih1, &whh1, &bih1, &bhh1, &outp, &flags, &h1ring, &h2ring };
    hipLaunchCooperativeKernel(lstm2_flow6, dim3(256), dim3(256), args, 0, stream);
}